// Round 3
// baseline (311.258 us; speedup 1.0000x reference)
//
#include <hip/hip_runtime.h>
#include <math.h>

// MeanShift: x (2,3,96,96) fp32. N=9216 pts/batch, C=3, 5 iterations of
// all-pairs Gaussian-weighted mean against ORIGINAL points.
//
// Scaled space: s = sqrt(50*log2e), so exp(-50*d2) == exp2(-||sy - sx||^2).
// u = 2y.p - |y|^2 - |p|^2, with -|p|^2 staged in p.w.
// 4 y's per thread: one ds_read_b128 feeds 4*(8 full-rate + 1 exp) = 96 busy
// cycles -> LDS pipe demand ~37% (2 y's saturated it at ~100%).

#define NPTS   9216            // 96*96
#define NB     2
#define MSPLIT 24              // m-slices per n-tile
#define SLICE  (NPTS / MSPLIT) // 384 m-points per block
#define WSLICE (SLICE / 4)     // 96 m-points per wave
#define NPB    256             // n-points per block (4 per thread)
#define NTILES (NPTS / NPB)    // 36
#define INV2BW2 50.0f
#define LOG2E   1.44269504088896340736f

// partial layout: part[(b*NPTS + n)*MSPLIT + k] = float4(num0,num1,num2,den)

__global__ __launch_bounds__(256) void ms_init(const float* __restrict__ x,
                                               float4* __restrict__ part,
                                               float s) {
    int gid = blockIdx.x * 256 + threadIdx.x;   // 0..18431
    int b = gid / NPTS;
    int n = gid - b * NPTS;
    const float* xb = x + b * 3 * NPTS;
    float4 p0;
    p0.x = xb[n] * s;
    p0.y = xb[NPTS + n] * s;
    p0.z = xb[2 * NPTS + n] * s;
    p0.w = 1.0f;                                // den=1 -> y0 = s*x
    float4* dst = part + (size_t)gid * MSPLIT;
    dst[0] = p0;
    float4 z = make_float4(0.f, 0.f, 0.f, 0.f);
#pragma unroll
    for (int k = 1; k < MSPLIT; ++k) dst[k] = z;
}

__global__ __launch_bounds__(256) void ms_iter(const float* __restrict__ x,
                                               const float4* __restrict__ pin,
                                               float4* __restrict__ pout,
                                               float s) {
    // overlay: phase 1 uses pts[384]+ypar[256] (10 KB); phase 2 uses red[1024]
    __shared__ float4 smem[4 * NPB];            // 16 KB
    float4* const pts  = smem;                  // [SLICE]
    float4* const ypar = smem + SLICE;          // [NPB]: (2y0,2y1,2y2,-|y|^2)
    float4* const red  = smem;                  // [4][NPB]

    const int tid  = threadIdx.x;
    const int lane = tid & 63;
    const int wv   = tid >> 6;
    const int k    = blockIdx.x % MSPLIT;
    const int tile = blockIdx.x / MSPLIT;
    const int b    = tile / NTILES;
    const int nt   = tile - b * NTILES;
    const int nbase = nt * NPB;
    const float* xb = x + b * 3 * NPTS;
    const int mbeg = k * SLICE;

    // Stage this block's m-slice into LDS, scaled, w = -|p|^2.
    for (int i = tid; i < SLICE; i += 256) {
        int g = mbeg + i;
        float px = xb[g] * s;
        float py = xb[NPTS + g] * s;
        float pz = xb[2 * NPTS + g] * s;
        float4 p;
        p.x = px; p.y = py; p.z = pz;
        p.w = -fmaf(px, px, fmaf(py, py, pz * pz));
        pts[i] = p;
    }

    // Combine previous partials ONCE per block: thread t -> n = nbase + t.
    {
        const float4* src = pin + (size_t)(b * NPTS + nbase + tid) * MSPLIT;
        float n0 = 0.f, n1 = 0.f, n2 = 0.f, dn = 0.f;
#pragma unroll
        for (int kk = 0; kk < MSPLIT; ++kk) {
            float4 p = src[kk];
            n0 += p.x; n1 += p.y; n2 += p.z; dn += p.w;
        }
        float inv = 1.0f / dn;
        float y0 = n0 * inv, y1 = n1 * inv, y2 = n2 * inv;
        float4 yp;
        yp.x = 2.f * y0; yp.y = 2.f * y1; yp.z = 2.f * y2;
        yp.w = -fmaf(y0, y0, fmaf(y1, y1, y2 * y2));   // -|y|^2
        ypar[tid] = yp;
    }
    __syncthreads();

    // Each thread: 4 y's (lane, lane+64, lane+128, lane+192).
    float4 yp0 = ypar[lane];
    float4 yp1 = ypar[lane + 64];
    float4 yp2 = ypar[lane + 128];
    float4 yp3 = ypar[lane + 192];

    float4 a0 = make_float4(0.f, 0.f, 0.f, 0.f);
    float4 a1 = make_float4(0.f, 0.f, 0.f, 0.f);
    float4 a2 = make_float4(0.f, 0.f, 0.f, 0.f);
    float4 a3 = make_float4(0.f, 0.f, 0.f, 0.f);

    const float4* pw = pts + wv * WSLICE;
#pragma unroll 4
    for (int i = 0; i < WSLICE; ++i) {
        float4 p = pw[i];
        float u0 = fmaf(p.x, yp0.x, fmaf(p.y, yp0.y, fmaf(p.z, yp0.z, p.w + yp0.w)));
        float u1 = fmaf(p.x, yp1.x, fmaf(p.y, yp1.y, fmaf(p.z, yp1.z, p.w + yp1.w)));
        float u2 = fmaf(p.x, yp2.x, fmaf(p.y, yp2.y, fmaf(p.z, yp2.z, p.w + yp2.w)));
        float u3 = fmaf(p.x, yp3.x, fmaf(p.y, yp3.y, fmaf(p.z, yp3.z, p.w + yp3.w)));
        float w0 = __builtin_amdgcn_exp2f(u0);
        float w1 = __builtin_amdgcn_exp2f(u1);
        float w2 = __builtin_amdgcn_exp2f(u2);
        float w3 = __builtin_amdgcn_exp2f(u3);
        a0.x = fmaf(w0, p.x, a0.x); a0.y = fmaf(w0, p.y, a0.y);
        a0.z = fmaf(w0, p.z, a0.z); a0.w += w0;
        a1.x = fmaf(w1, p.x, a1.x); a1.y = fmaf(w1, p.y, a1.y);
        a1.z = fmaf(w1, p.z, a1.z); a1.w += w1;
        a2.x = fmaf(w2, p.x, a2.x); a2.y = fmaf(w2, p.y, a2.y);
        a2.z = fmaf(w2, p.z, a2.z); a2.w += w2;
        a3.x = fmaf(w3, p.x, a3.x); a3.y = fmaf(w3, p.y, a3.y);
        a3.z = fmaf(w3, p.z, a3.z); a3.w += w3;
    }

    // Cross-wave reduction; smem is reused -> barrier first (pts dead after loop).
    __syncthreads();
    red[wv * NPB + lane]       = a0;
    red[wv * NPB + lane + 64]  = a1;
    red[wv * NPB + lane + 128] = a2;
    red[wv * NPB + lane + 192] = a3;
    __syncthreads();
    {
        float4 r0 = red[tid];
        float4 r1 = red[NPB + tid];
        float4 r2 = red[2 * NPB + tid];
        float4 r3 = red[3 * NPB + tid];
        float4 o;
        o.x = (r0.x + r1.x) + (r2.x + r3.x);
        o.y = (r0.y + r1.y) + (r2.y + r3.y);
        o.z = (r0.z + r1.z) + (r2.z + r3.z);
        o.w = (r0.w + r1.w) + (r2.w + r3.w);
        pout[(size_t)(b * NPTS + nbase + tid) * MSPLIT + k] = o;
    }
}

__global__ __launch_bounds__(256) void ms_pack(const float4* __restrict__ part,
                                               float* __restrict__ out,
                                               float invs) {
    int gid = blockIdx.x * 256 + threadIdx.x;
    int b = gid / NPTS;
    int n = gid - b * NPTS;
    const float4* src = part + (size_t)gid * MSPLIT;
    float n0 = 0.f, n1 = 0.f, n2 = 0.f, dn = 0.f;
#pragma unroll
    for (int kk = 0; kk < MSPLIT; ++kk) {
        float4 p = src[kk];
        n0 += p.x; n1 += p.y; n2 += p.z; dn += p.w;
    }
    float f = invs / dn;                        // unscale + normalize
    float* ob = out + b * 3 * NPTS;
    ob[n]            = n0 * f;
    ob[NPTS + n]     = n1 * f;
    ob[2 * NPTS + n] = n2 * f;
}

extern "C" void kernel_launch(void* const* d_in, const int* in_sizes, int n_in,
                              void* d_out, int out_size, void* d_ws, size_t ws_size,
                              hipStream_t stream) {
    const float* x = (const float*)d_in[0];
    float* out = (float*)d_out;
    const float s = sqrtf(INV2BW2 * LOG2E);     // 8.4932...

    float4* pa = (float4*)d_ws;                                  // 7.08 MB
    float4* pb = pa + (size_t)NB * NPTS * MSPLIT;                // 7.08 MB

    ms_init<<<NB * NPTS / 256, 256, 0, stream>>>(x, pa, s);
    float4* cur = pa;
    float4* nxt = pb;
    for (int it = 0; it < 5; ++it) {
        ms_iter<<<NB * NTILES * MSPLIT, 256, 0, stream>>>(x, cur, nxt, s);
        float4* t = cur; cur = nxt; nxt = t;
    }
    ms_pack<<<NB * NPTS / 256, 256, 0, stream>>>(cur, out, 1.0f / s);
}

// Round 4
// 243.428 us; speedup vs baseline: 1.2786x; 1.2786x over previous
//
#include <hip/hip_runtime.h>
#include <math.h>

// MeanShift: x (2,3,96,96) fp32, 5 iters of all-pairs Gaussian-weighted mean.
// Scaled space: s = sqrt(50*log2e) -> w = exp2(2p.y - |p|^2 - |y|^2) (scaled).
// Hot loop packed over m (v_pk_fma_f32): SoA LDS holds (2px, 2py, 2pz, -|p|^2);
// y-side splats are loop-invariant. exp2 stays scalar (1/pair, ~16 cyc/wave).
// Inter-iteration (num,den) exchanged via atomicAdd into pre-zeroed buffers
// (removes the x24-redundant partial reads of rounds 2-3).

typedef float v2f __attribute__((ext_vector_type(2)));

#define NPTS   9216            // 96*96
#define NB     2
#define TOT    (NB * NPTS)     // 18432
#define MSPLIT 24              // m-slices per n-tile
#define SLICE  (NPTS / MSPLIT) // 384 m per block
#define WSLICE (SLICE / 4)     // 96 m per wave
#define NPB    256             // n per block (4 per thread)
#define NTILES (NPTS / NPB)    // 36
#define INV2BW2 50.0f
#define LOG2E   1.44269504088896340736f

// acc[t][gid] = float4(num0,num1,num2,den) for iteration t (t=0..5), scaled pts.

__global__ __launch_bounds__(256) void ms_init(const float* __restrict__ x,
                                               float4* __restrict__ acc,
                                               float s) {
    int gid = blockIdx.x * 256 + threadIdx.x;   // < TOT
    int b = gid / NPTS;
    int n = gid - b * NPTS;
    const float* xb = x + b * 3 * NPTS;
    acc[gid] = make_float4(xb[n] * s, xb[NPTS + n] * s, xb[2 * NPTS + n] * s, 1.0f);
    float4 z = make_float4(0.f, 0.f, 0.f, 0.f);
#pragma unroll
    for (int t = 1; t < 6; ++t) acc[(size_t)t * TOT + gid] = z;
}

__global__ __launch_bounds__(256, 4) void ms_iter(const float* __restrict__ x,
                                                  const float4* __restrict__ accIn,
                                                  float4* __restrict__ accOut,
                                                  float s) {
    __shared__ float4 smem[1024];               // 16 KB
    float* const xs = (float*)smem;             // [SLICE] = 2*px
    float* const ys = xs + SLICE;               // 2*py
    float* const zs = ys + SLICE;               // 2*pz
    float* const ws = zs + SLICE;               // -|p|^2
    float4* const ypar = smem + SLICE;          // [NPB] (4*SLICE floats == SLICE float4)
    float4* const red  = smem;                  // [4][NPB] overlay (post-loop)

    const int tid  = threadIdx.x;
    const int lane = tid & 63;
    const int wv   = tid >> 6;
    const int k    = blockIdx.x % MSPLIT;
    const int tile = blockIdx.x / MSPLIT;
    const int b    = tile / NTILES;
    const int nt   = tile - b * NTILES;
    const int nbase = nt * NPB;
    const float* xb = x + b * 3 * NPTS;
    const int mbeg = k * SLICE;

    // SoA staging, scaled, 2x folded into coords.
    for (int i = tid; i < SLICE; i += 256) {
        int g = mbeg + i;
        float px = xb[g] * s;
        float py = xb[NPTS + g] * s;
        float pz = xb[2 * NPTS + g] * s;
        xs[i] = 2.f * px;
        ys[i] = 2.f * py;
        zs[i] = 2.f * pz;
        ws[i] = -fmaf(px, px, fmaf(py, py, pz * pz));
    }
    // y for this iteration: single coalesced float4 per n (no x24 redundancy).
    {
        float4 a = accIn[b * NPTS + nbase + tid];
        float inv = 1.0f / a.w;
        float y0 = a.x * inv, y1 = a.y * inv, y2 = a.z * inv;
        ypar[tid] = make_float4(y0, y1, y2, -fmaf(y0, y0, fmaf(y1, y1, y2 * y2)));
    }
    __syncthreads();

    // Loop-invariant packed y constants (4 y's per thread).
    v2f Yx[4], Yy[4], Yz[4], Yw[4];
    v2f Ax[4], Ay[4], Az[4], Aw[4];
#pragma unroll
    for (int j = 0; j < 4; ++j) {
        float4 yp = ypar[lane + 64 * j];
        Yx[j] = (v2f){yp.x, yp.x};
        Yy[j] = (v2f){yp.y, yp.y};
        Yz[j] = (v2f){yp.z, yp.z};
        Yw[j] = (v2f){yp.w, yp.w};
        Ax[j] = (v2f){0.f, 0.f}; Ay[j] = (v2f){0.f, 0.f};
        Az[j] = (v2f){0.f, 0.f}; Aw[j] = (v2f){0.f, 0.f};
    }

    const float* xsw = xs + wv * WSLICE;
    const float* ysw = ys + wv * WSLICE;
    const float* zsw = zs + wv * WSLICE;
    const float* wsw = ws + wv * WSLICE;

    for (int i = 0; i < WSLICE; i += 4) {       // 4 m per superiter
        float4 PX = *(const float4*)(xsw + i);
        float4 PY = *(const float4*)(ysw + i);
        float4 PZ = *(const float4*)(zsw + i);
        float4 PW = *(const float4*)(wsw + i);
        v2f px0 = (v2f){PX.x, PX.y}, px1 = (v2f){PX.z, PX.w};
        v2f py0 = (v2f){PY.x, PY.y}, py1 = (v2f){PY.z, PY.w};
        v2f pz0 = (v2f){PZ.x, PZ.y}, pz1 = (v2f){PZ.z, PZ.w};
        v2f pw0 = (v2f){PW.x, PW.y}, pw1 = (v2f){PW.z, PW.w};
#pragma unroll
        for (int j = 0; j < 4; ++j) {
            v2f t0 = pw0 + Yw[j];
            t0 = __builtin_elementwise_fma(pz0, Yz[j], t0);
            t0 = __builtin_elementwise_fma(py0, Yy[j], t0);
            t0 = __builtin_elementwise_fma(px0, Yx[j], t0);
            v2f t1 = pw1 + Yw[j];
            t1 = __builtin_elementwise_fma(pz1, Yz[j], t1);
            t1 = __builtin_elementwise_fma(py1, Yy[j], t1);
            t1 = __builtin_elementwise_fma(px1, Yx[j], t1);
            v2f w0, w1;
            w0.x = __builtin_amdgcn_exp2f(t0.x);
            w0.y = __builtin_amdgcn_exp2f(t0.y);
            w1.x = __builtin_amdgcn_exp2f(t1.x);
            w1.y = __builtin_amdgcn_exp2f(t1.y);
            Ax[j] = __builtin_elementwise_fma(w0, px0, Ax[j]);
            Ay[j] = __builtin_elementwise_fma(w0, py0, Ay[j]);
            Az[j] = __builtin_elementwise_fma(w0, pz0, Az[j]);
            Aw[j] += w0;
            Ax[j] = __builtin_elementwise_fma(w1, px1, Ax[j]);
            Ay[j] = __builtin_elementwise_fma(w1, py1, Ay[j]);
            Az[j] = __builtin_elementwise_fma(w1, pz1, Az[j]);
            Aw[j] += w1;
        }
    }

    // Cross-wave reduction (red overlays pts/ypar; both dead now).
    __syncthreads();
#pragma unroll
    for (int j = 0; j < 4; ++j) {
        red[wv * NPB + lane + 64 * j] =
            make_float4(Ax[j].x + Ax[j].y, Ay[j].x + Ay[j].y,
                        Az[j].x + Az[j].y, Aw[j].x + Aw[j].y);
    }
    __syncthreads();
    {
        float4 r0 = red[tid];
        float4 r1 = red[NPB + tid];
        float4 r2 = red[2 * NPB + tid];
        float4 r3 = red[3 * NPB + tid];
        // coords were accumulated with the 2x fold -> scale by 0.5
        float ox = 0.5f * ((r0.x + r1.x) + (r2.x + r3.x));
        float oy = 0.5f * ((r0.y + r1.y) + (r2.y + r3.y));
        float oz = 0.5f * ((r0.z + r1.z) + (r2.z + r3.z));
        float od = (r0.w + r1.w) + (r2.w + r3.w);
        float* dst = (float*)&accOut[b * NPTS + nbase + tid];
        atomicAdd(dst + 0, ox);
        atomicAdd(dst + 1, oy);
        atomicAdd(dst + 2, oz);
        atomicAdd(dst + 3, od);
    }
}

__global__ __launch_bounds__(256) void ms_pack(const float4* __restrict__ acc5,
                                               float* __restrict__ out,
                                               float invs) {
    int gid = blockIdx.x * 256 + threadIdx.x;
    int b = gid / NPTS;
    int n = gid - b * NPTS;
    float4 a = acc5[gid];
    float f = invs / a.w;                       // unscale + normalize
    float* ob = out + b * 3 * NPTS;
    ob[n]            = a.x * f;
    ob[NPTS + n]     = a.y * f;
    ob[2 * NPTS + n] = a.z * f;
}

extern "C" void kernel_launch(void* const* d_in, const int* in_sizes, int n_in,
                              void* d_out, int out_size, void* d_ws, size_t ws_size,
                              hipStream_t stream) {
    const float* x = (const float*)d_in[0];
    float* out = (float*)d_out;
    const float s = sqrtf(INV2BW2 * LOG2E);     // 8.4932...

    float4* acc = (float4*)d_ws;                // 6 * TOT * 16 B = 1.77 MB

    ms_init<<<TOT / 256, 256, 0, stream>>>(x, acc, s);
    for (int it = 0; it < 5; ++it) {
        ms_iter<<<NB * NTILES * MSPLIT, 256, 0, stream>>>(
            x, acc + (size_t)it * TOT, acc + (size_t)(it + 1) * TOT, s);
    }
    ms_pack<<<TOT / 256, 256, 0, stream>>>(acc + (size_t)5 * TOT, out, 1.0f / s);
}